// Round 2
// baseline (2570.805 us; speedup 1.0000x reference)
//
#include <hip/hip_runtime.h>
#include <stdint.h>

// Problem constants (fixed by setup_inputs): B=16, N=2048, D=768
#define BB 16
#define NN 2048
#define DD 768
#define BN (BB*NN)          // 32768 rows per tensor

// ---------------------------------------------------------------------------
// ws layout (float-element offsets into d_ws):
//  [0,      32768)  invq  (1/||q_row||)
//  [32768,  65536)  invc  (1/||c_row||)
//  [65536, 196608)  pmax  [b][ms(4)][n]  partial max over m-subset
//  [196608,327680)  pidx  (int) matching argmax
//  [327680,360448)  rm    final reuse_map (f32)
//  [360448,393216)  fidx  (int) final argmax
// total 1.5 MB
// ---------------------------------------------------------------------------

// --- Kernel 1: per-row inverse L2 norms for query_input and cached_input ----
// one wave per row; rows [0,BN) = q, [BN,2BN) = c. ws[row] works for both
// because invc immediately follows invq in the workspace.
__global__ __launch_bounds__(256) void norms_kernel(
        const float* __restrict__ qi, const float* __restrict__ ci,
        float* __restrict__ ws) {
    int row  = blockIdx.x * 4 + (threadIdx.x >> 6);
    int lane = threadIdx.x & 63;
    const float* src = (row < BN) ? qi : ci;
    int r = row & (BN - 1);
    const float4* p = (const float4*)(src + (size_t)r * DD);
    float s = 0.0f;
#pragma unroll
    for (int k = 0; k < 3; k++) {          // 192 float4 per row / 64 lanes
        float4 v = p[lane + 64 * k];
        s += v.x * v.x + v.y * v.y + v.z * v.z + v.w * v.w;
    }
#pragma unroll
    for (int off = 32; off; off >>= 1) s += __shfl_xor(s, off);
    if (lane == 0) ws[row] = 1.0f / sqrtf(s);
}

// --- Kernel 2: fused GEMM + running max/argmax over M -----------------------
// grid (ntile=16, msplit=4, b=16) = 1024 blocks (4/CU). 128x128 tile,
// 8x8 per thread, K chunked by 16 through LDS. Each block covers m-tiles
// {ms, ms+4, ms+8, ms+12} (ascending -> first-occurrence tie semantics hold).
__global__ __launch_bounds__(256, 4) void simmax_kernel(
        const float* __restrict__ qi, const float* __restrict__ ci,
        const float* __restrict__ invc,
        float* __restrict__ pmax, int* __restrict__ pidx) {
    __shared__ float qs[16][128];
    __shared__ float cs[16][128];
    const int t  = threadIdx.x;
    const int tx = t & 15, ty = t >> 4;
    const int n0 = blockIdx.x * 128;
    const int ms = blockIdx.y;
    const int b  = blockIdx.z;
    const size_t qbase = ((size_t)b * NN + n0) * DD;
    const int sr = t >> 1;            // staged row 0..127 (two lanes per row)
    const int sc = (t & 1) * 8;       // staged k-offset 0 or 8

    float rmax[8]; int ridx[8];
#pragma unroll
    for (int i = 0; i < 8; i++) { rmax[i] = -3.0e38f; ridx[i] = 0; }

    for (int mt = ms; mt < 16; mt += 4) {
        const int m0 = mt * 128;
        const size_t cbase = ((size_t)b * NN + m0) * DD;
        float acc[8][8];
#pragma unroll
        for (int i = 0; i < 8; i++)
#pragma unroll
            for (int j = 0; j < 8; j++) acc[i][j] = 0.0f;

        for (int k0 = 0; k0 < DD; k0 += 16) {
            __syncthreads();   // protect LDS from previous chunk's readers
            const float* gq = qi + qbase + (size_t)sr * DD + k0 + sc;
            const float* gc = ci + cbase + (size_t)sr * DD + k0 + sc;
            float4 v0 = *(const float4*)(gq);
            float4 v1 = *(const float4*)(gq + 4);
            float4 w0 = *(const float4*)(gc);
            float4 w1 = *(const float4*)(gc + 4);
            qs[sc + 0][sr] = v0.x; qs[sc + 1][sr] = v0.y;
            qs[sc + 2][sr] = v0.z; qs[sc + 3][sr] = v0.w;
            qs[sc + 4][sr] = v1.x; qs[sc + 5][sr] = v1.y;
            qs[sc + 6][sr] = v1.z; qs[sc + 7][sr] = v1.w;
            cs[sc + 0][sr] = w0.x; cs[sc + 1][sr] = w0.y;
            cs[sc + 2][sr] = w0.z; cs[sc + 3][sr] = w0.w;
            cs[sc + 4][sr] = w1.x; cs[sc + 5][sr] = w1.y;
            cs[sc + 6][sr] = w1.z; cs[sc + 7][sr] = w1.w;
            __syncthreads();
#pragma unroll
            for (int kk = 0; kk < 16; kk++) {
                // rows/cols split as {x*4 .. x*4+3} U {64+x*4 ..}: all b128
                // reads are conflict-free or 2-way (free, m136)
                float4 a0 = *(const float4*)&qs[kk][ty * 4];
                float4 a1 = *(const float4*)&qs[kk][64 + ty * 4];
                float4 b0 = *(const float4*)&cs[kk][tx * 4];
                float4 b1 = *(const float4*)&cs[kk][64 + tx * 4];
                float ar[8] = {a0.x, a0.y, a0.z, a0.w, a1.x, a1.y, a1.z, a1.w};
                float br[8] = {b0.x, b0.y, b0.z, b0.w, b1.x, b1.y, b1.z, b1.w};
#pragma unroll
                for (int i = 0; i < 8; i++)
#pragma unroll
                    for (int j = 0; j < 8; j++)
                        acc[i][j] = fmaf(ar[i], br[j], acc[i][j]);
            }
        }
        // fold this m-tile into the running (max, argmax); argmax is over
        // dot*invc (invq>0 is row-constant, applied at merge)
#pragma unroll
        for (int j = 0; j < 8; j++) {
            int col  = m0 + ((j < 4) ? tx * 4 + j : 64 + tx * 4 + (j - 4));
            float cv = invc[b * NN + col];
#pragma unroll
            for (int i = 0; i < 8; i++) {
                float val = acc[i][j] * cv;
                if (val > rmax[i]) { rmax[i] = val; ridx[i] = col; }
            }
        }
    }

    // reduce across tx (16 consecutive lanes share a ty => same rows)
#pragma unroll
    for (int i = 0; i < 8; i++) {
        float m = rmax[i]; int id = ridx[i];
#pragma unroll
        for (int off = 1; off < 16; off <<= 1) {
            float om = __shfl_xor(m, off);
            int   oi = __shfl_xor(id, off);
            if (om > m || (om == m && oi < id)) { m = om; id = oi; }
        }
        if (tx == 0) {
            int gr = n0 + ((i < 4) ? ty * 4 + i : 64 + ty * 4 + (i - 4));
            pmax[(b * 4 + ms) * NN + gr] = m;
            pidx[(b * 4 + ms) * NN + gr] = id;
        }
    }
}

// --- Kernel 3: merge 4 m-split partials, apply invq + sigmoid threshold ----
__global__ __launch_bounds__(256) void merge_kernel(
        const float* __restrict__ pmax, const int* __restrict__ pidx,
        const float* __restrict__ invq, const float* __restrict__ st,
        float* __restrict__ out_map,
        float* __restrict__ ws_rm, int* __restrict__ ws_idx) {
    int id = blockIdx.x * 256 + threadIdx.x;   // [0, BN)
    int b = id >> 11, n = id & 2047;
    float best = pmax[(b * 4) * NN + n];
    int   bi   = pidx[(b * 4) * NN + n];
#pragma unroll
    for (int s = 1; s < 4; s++) {
        float p = pmax[(b * 4 + s) * NN + n];
        int   q = pidx[(b * 4 + s) * NN + n];
        if (p > best || (p == best && q < bi)) { best = p; bi = q; }
    }
    float score = best * invq[id];
    float thr   = 1.0f / (1.0f + expf(-st[n]));
    float rm    = 1.0f / (1.0f + expf(-40.0f * (score - thr)));
    out_map[id] = rm;
    ws_rm[id]   = rm;
    ws_idx[id]  = bi;
}

// --- Kernel 4: gather + blend, f32 stores ----------------------------------
__global__ __launch_bounds__(256) void blend_kernel(
        const float* __restrict__ qi, const float* __restrict__ qv,
        const float* __restrict__ ci, const float* __restrict__ cv,
        const float* __restrict__ ws_rm, const int* __restrict__ ws_idx,
        float* __restrict__ out_ri, float* __restrict__ out_rv) {
    int row  = blockIdx.x * 4 + (threadIdx.x >> 6);
    int lane = threadIdx.x & 63;
    float rm  = ws_rm[row];
    int gidx  = ws_idx[row];
    int b     = row >> 11;
    float om  = 1.0f - rm;
    const float4* q4 = (const float4*)(qi + (size_t)row * DD);
    const float4* v4 = (const float4*)(qv + (size_t)row * DD);
    const float4* s4 = (const float4*)(ci + ((size_t)b * NN + gidx) * DD);
    const float4* w4 = (const float4*)(cv + ((size_t)b * NN + gidx) * DD);
    float4* ori = (float4*)(out_ri + (size_t)row * DD);
    float4* orv = (float4*)(out_rv + (size_t)row * DD);
#pragma unroll
    for (int k = 0; k < 3; k++) {
        int f = lane + 64 * k;
        float4 a = q4[f], si = s4[f];
        float4 o;
        o.x = om * a.x + rm * si.x;
        o.y = om * a.y + rm * si.y;
        o.z = om * a.z + rm * si.z;
        o.w = om * a.w + rm * si.w;
        ori[f] = o;
        float4 av = v4[f], sv = w4[f];
        float4 p;
        p.x = om * av.x + rm * sv.x;
        p.y = om * av.y + rm * sv.y;
        p.z = om * av.z + rm * sv.z;
        p.w = om * av.w + rm * sv.w;
        orv[f] = p;
    }
}

extern "C" void kernel_launch(void* const* d_in, const int* in_sizes, int n_in,
                              void* d_out, int out_size, void* d_ws, size_t ws_size,
                              hipStream_t stream) {
    const float* qi = (const float*)d_in[0];
    const float* qv = (const float*)d_in[1];
    const float* ci = (const float*)d_in[2];
    const float* cv = (const float*)d_in[3];
    const float* st = (const float*)d_in[4];

    float* ws    = (float*)d_ws;
    float* invq  = ws;
    float* invc  = ws + 32768;
    float* pmax  = ws + 65536;
    int*   pidx  = (int*)(ws + 196608);
    float* ws_rm = ws + 327680;
    int*   ws_id = (int*)(ws + 360448);

    float* out     = (float*)d_out;   // f32 outputs, concatenated in return order
    float* out_map = out;                                  // [B,N]
    float* out_ri  = out + 32768;                          // [B,N,D]
    float* out_rv  = out + 32768 + (size_t)BN * DD;        // [B,N,D]

    norms_kernel<<<(2 * BN) / 4, 256, 0, stream>>>(qi, ci, ws);
    dim3 g2(16, 4, BB);
    simmax_kernel<<<g2, 256, 0, stream>>>(qi, ci, invc, pmax, pidx);
    merge_kernel<<<BN / 256, 256, 0, stream>>>(pmax, pidx, invq, st,
                                               out_map, ws_rm, ws_id);
    blend_kernel<<<BN / 4, 256, 0, stream>>>(qi, qv, ci, cv, ws_rm, ws_id,
                                             out_ri, out_rv);
}